// Round 1
// baseline (428.757 us; speedup 1.0000x reference)
//
#include <hip/hip_runtime.h>
#include <hip/hip_bf16.h>

// B=4, S=2048, D=1024, E=8, H=512, K(top)=2
#define TOKENS 8192
#define D_DIM  1024
#define E_NUM  8
#define H_DIM  512
#define N1     4608   // E*H + H  (columns of GEMM1 / K of GEMM2)

typedef __bf16 bf16_t;
typedef __bf16 bf16x8 __attribute__((ext_vector_type(8)));
typedef __bf16 bf16x4 __attribute__((ext_vector_type(4)));
typedef float  f32x4  __attribute__((ext_vector_type(4)));

// ---------------------------------------------------------------- routing
// one wave per token: scores = sigmoid(x @ gate_W) * route_scale, top-2,
// normalized weights scattered into dense gate[tok][8] (fp64 accum so our
// top-2 selection matches the reference even for near-tied scores).
__global__ __launch_bounds__(256) void routing_kernel(
    const float* __restrict__ x, const float* __restrict__ gW,
    const float* __restrict__ route_scale, float* __restrict__ gate) {
  int tok  = blockIdx.x * 4 + (threadIdx.x >> 6);
  int lane = threadIdx.x & 63;
  const float* xr = x + (size_t)tok * D_DIM;
  double p[E_NUM];
#pragma unroll
  for (int e = 0; e < E_NUM; ++e) p[e] = 0.0;
  for (int d = lane; d < D_DIM; d += 64) {
    double xv = (double)xr[d];
    const float* g = gW + (size_t)d * E_NUM;
#pragma unroll
    for (int e = 0; e < E_NUM; ++e) p[e] += xv * (double)g[e];
  }
#pragma unroll
  for (int off = 32; off > 0; off >>= 1) {
#pragma unroll
    for (int e = 0; e < E_NUM; ++e) p[e] += __shfl_xor(p[e], off, 64);
  }
  if (lane == 0) {
    double rs = (double)route_scale[0];
    double s[E_NUM];
#pragma unroll
    for (int e = 0; e < E_NUM; ++e) s[e] = rs / (1.0 + exp(-p[e]));
    int i1 = 0;
#pragma unroll
    for (int e = 1; e < E_NUM; ++e) if (s[e] > s[i1]) i1 = e;
    int i2 = (i1 == 0) ? 1 : 0;
#pragma unroll
    for (int e = 0; e < E_NUM; ++e) if (e != i1 && s[e] > s[i2]) i2 = e;
    double inv = 1.0 / (s[i1] + s[i2]);
    float o[E_NUM];
#pragma unroll
    for (int e = 0; e < E_NUM; ++e) o[e] = 0.f;
    o[i1] = (float)(s[i1] * inv);
    o[i2] = (float)(s[i2] * inv);
#pragma unroll
    for (int e = 0; e < E_NUM; ++e) gate[(size_t)tok * 8 + e] = o[e];
  }
}

// ---------------------------------------------------------------- cast x -> bf16
__global__ __launch_bounds__(256) void castx_kernel(
    const float* __restrict__ x, bf16_t* __restrict__ Xb, int n4) {
  int i = blockIdx.x * blockDim.x + threadIdx.x;
  for (; i < n4; i += gridDim.x * blockDim.x) {
    float4 v = ((const float4*)x)[i];
    bf16x4 o = { (bf16_t)v.x, (bf16_t)v.y, (bf16_t)v.z, (bf16_t)v.w };
    ((bf16x4*)Xb)[i] = o;
  }
}

// ------------------------------------------------- repack W1''/Ws1 -> Bt1 (N1 x 1024) bf16
// Bt1[n][k] = (n<4096) ? W1[e= n>>9][d=k][h=n&511] : Ws1[k][n-4096]
__global__ __launch_bounds__(256) void repack1_kernel(
    const float* __restrict__ W1, const float* __restrict__ Ws1,
    bf16_t* __restrict__ Bt1) {
  __shared__ float tile[32][33];
  int k0 = blockIdx.x * 32, n0 = blockIdx.y * 32;
  int tx = threadIdx.x, ty = threadIdx.y;
#pragma unroll
  for (int i = 0; i < 4; ++i) {
    int kl = ty + i * 8;
    int n = n0 + tx, k = k0 + kl;
    float v;
    if (n0 < 4096) v = W1[(size_t)(n >> 9) * (D_DIM * H_DIM) + (size_t)k * H_DIM + (n & 511)];
    else           v = Ws1[(size_t)k * H_DIM + (n - 4096)];
    tile[kl][tx] = v;
  }
  __syncthreads();
#pragma unroll
  for (int i = 0; i < 4; ++i) {
    int nl = ty + i * 8;
    Bt1[(size_t)(n0 + nl) * D_DIM + k0 + tx] = (bf16_t)tile[tx][nl];
  }
}

// ------------------------------------------------- repack W2''/Ws2 -> Bt2 (1024 x N1) bf16
// Bt2[d][k] = (k<4096) ? W2flat[k*1024+d] : Ws2[(k-4096)*1024+d]
__global__ __launch_bounds__(256) void repack2_kernel(
    const float* __restrict__ W2, const float* __restrict__ Ws2,
    bf16_t* __restrict__ Bt2) {
  __shared__ float tile[32][33];
  int d0 = blockIdx.x * 32, k0 = blockIdx.y * 32;
  int tx = threadIdx.x, ty = threadIdx.y;
#pragma unroll
  for (int i = 0; i < 4; ++i) {
    int kl = ty + i * 8;
    int k = k0 + kl, d = d0 + tx;
    float v = (k0 < 4096) ? W2[(size_t)k * D_DIM + d]
                          : Ws2[(size_t)(k - 4096) * D_DIM + d];
    tile[kl][tx] = v;
  }
  __syncthreads();
#pragma unroll
  for (int i = 0; i < 4; ++i) {
    int dl = ty + i * 8;
    Bt2[(size_t)(d0 + dl) * N1 + k0 + tx] = (bf16_t)tile[tx][dl];
  }
}

// ---------------------------------------------------------------- GEMM (m97 structure)
// C(MxN) = A(MxK, row-major bf16) @ B^T(NxK, row-major bf16)
// 128x128 tile, BK=32, 4 waves in 2x2, each wave 64x64 (4x4 16x16x32 MFMA frags).
// EPI=1: H'' = bf16( gate * gelu(acc + b1'') )   EPI=2: out = f32( acc + bs2 + sum_e g_e b2[e] )
template <int EPI>
__global__ __launch_bounds__(256) void gemm_bt_kernel(
    const bf16_t* __restrict__ A, const bf16_t* __restrict__ B,
    int K,
    const float* __restrict__ gate,
    const float* __restrict__ b1, const float* __restrict__ bs1, bf16_t* __restrict__ Hout,
    const float* __restrict__ b2, const float* __restrict__ bs2, float* __restrict__ Fout) {
  __shared__ bf16_t sA[128 * 32];
  __shared__ bf16_t sB[128 * 32];
  const int t = threadIdx.x;
  const int wave = t >> 6, lane = t & 63;
  const int wr = wave >> 1, wc = wave & 1;
  const int m0 = blockIdx.y * 128, n0 = blockIdx.x * 128;
  const int NOUT = (EPI == 1) ? N1 : D_DIM;

  f32x4 acc[4][4];
#pragma unroll
  for (int i = 0; i < 4; ++i)
#pragma unroll
    for (int j = 0; j < 4; ++j) acc[i][j] = (f32x4){0.f, 0.f, 0.f, 0.f};

  for (int k0 = 0; k0 < K; k0 += 32) {
#pragma unroll
    for (int i = 0; i < 2; ++i) {
      int o = (i * 256 + t) * 16;     // byte offset within the 8 KiB tile
      int row = o >> 6;               // 64 B per LDS row (32 bf16)
      int colb = o & 63;
      char* ga = (char*)A + ((size_t)(m0 + row) * K + k0) * 2 + colb;
      __builtin_amdgcn_global_load_lds(
          (__attribute__((address_space(1))) void*)ga,
          (__attribute__((address_space(3))) void*)((char*)sA + i * 4096 + wave * 1024),
          16, 0, 0);
      char* gb = (char*)B + ((size_t)(n0 + row) * K + k0) * 2 + colb;
      __builtin_amdgcn_global_load_lds(
          (__attribute__((address_space(1))) void*)gb,
          (__attribute__((address_space(3))) void*)((char*)sB + i * 4096 + wave * 1024),
          16, 0, 0);
    }
    __syncthreads();
    bf16x8 af[4], bfv[4];
    const int kb = (lane >> 4) * 16;      // byte offset of this lane's k-chunk
    const int ar = wr * 64 + (lane & 15);
    const int br = wc * 64 + (lane & 15);
#pragma unroll
    for (int m = 0; m < 4; ++m)
      af[m] = *(const bf16x8*)((const char*)sA + (size_t)(ar + m * 16) * 64 + kb);
#pragma unroll
    for (int n = 0; n < 4; ++n)
      bfv[n] = *(const bf16x8*)((const char*)sB + (size_t)(br + n * 16) * 64 + kb);
#pragma unroll
    for (int m = 0; m < 4; ++m)
#pragma unroll
      for (int n = 0; n < 4; ++n)
        acc[m][n] = __builtin_amdgcn_mfma_f32_16x16x32_bf16(af[m], bfv[n], acc[m][n], 0, 0, 0);
    __syncthreads();
  }

  if (EPI == 1) {
    const bool shb = (n0 >= 4096);       // shared-expert column band (gate = 1)
    const int eb = n0 >> 9;              // 128-col block lies in exactly one expert band
#pragma unroll
    for (int m = 0; m < 4; ++m) {
      const int rb = m0 + wr * 64 + m * 16 + (lane >> 4) * 4;
#pragma unroll
      for (int n = 0; n < 4; ++n) {
        const int col = n0 + wc * 64 + n * 16 + (lane & 15);
        const float bias = shb ? bs1[col - 4096] : b1[col];  // b1 flat (E*H) == col
#pragma unroll
        for (int r = 0; r < 4; ++r) {
          const int row = rb + r;
          float v = acc[m][n][r] + bias;
          v = 0.5f * v * (1.f + erff(v * 0.70710678118654752f));  // exact gelu
          const float g = shb ? 1.0f : gate[(size_t)row * 8 + eb];
          Hout[(size_t)row * NOUT + col] = (bf16_t)(v * g);
        }
      }
    }
  } else {
#pragma unroll
    for (int m = 0; m < 4; ++m) {
      const int rb = m0 + wr * 64 + m * 16 + (lane >> 4) * 4;
#pragma unroll
      for (int n = 0; n < 4; ++n) {
        const int col = n0 + wc * 64 + n * 16 + (lane & 15);
        float bb[E_NUM];
#pragma unroll
        for (int e = 0; e < E_NUM; ++e) bb[e] = b2[(size_t)e * D_DIM + col];
        const float bias0 = bs2[col];
#pragma unroll
        for (int r = 0; r < 4; ++r) {
          const int row = rb + r;
          float v = acc[m][n][r] + bias0;
          const float* gr = gate + (size_t)row * 8;
#pragma unroll
          for (int e = 0; e < E_NUM; ++e) v += gr[e] * bb[e];
          Fout[(size_t)row * NOUT + col] = v;
        }
      }
    }
  }
}

// ---------------------------------------------------------------- launch
extern "C" void kernel_launch(void* const* d_in, const int* in_sizes, int n_in,
                              void* d_out, int out_size, void* d_ws, size_t ws_size,
                              hipStream_t stream) {
  (void)in_sizes; (void)n_in; (void)out_size; (void)ws_size;
  const float* x    = (const float*)d_in[0];
  const float* gW   = (const float*)d_in[1];
  const float* W1   = (const float*)d_in[2];
  const float* b1   = (const float*)d_in[3];
  const float* W2   = (const float*)d_in[4];
  const float* b2   = (const float*)d_in[5];
  const float* Ws1  = (const float*)d_in[6];
  const float* bs1  = (const float*)d_in[7];
  const float* Ws2  = (const float*)d_in[8];
  const float* bs2  = (const float*)d_in[9];
  const float* rsc  = (const float*)d_in[10];
  float* out = (float*)d_out;

  char* w = (char*)d_ws;
  float*  gate = (float*)w;  w += (size_t)TOKENS * 8 * 4;            // 256 KiB
  bf16_t* Xb   = (bf16_t*)w; w += (size_t)TOKENS * D_DIM * 2;        // 16.8 MB
  bf16_t* Bt1  = (bf16_t*)w; w += (size_t)N1 * D_DIM * 2;            // 9.4 MB
  bf16_t* Bt2  = (bf16_t*)w; w += (size_t)D_DIM * N1 * 2;            // 9.4 MB
  bf16_t* Hm   = (bf16_t*)w; w += (size_t)TOKENS * N1 * 2;           // 75.5 MB

  routing_kernel<<<TOKENS / 4, 256, 0, stream>>>(x, gW, rsc, gate);
  castx_kernel<<<2048, 256, 0, stream>>>(x, Xb, TOKENS * D_DIM / 4);
  repack1_kernel<<<dim3(D_DIM / 32, N1 / 32), dim3(32, 8), 0, stream>>>(W1, Ws1, Bt1);
  repack2_kernel<<<dim3(D_DIM / 32, N1 / 32), dim3(32, 8), 0, stream>>>(W2, Ws2, Bt2);

  gemm_bt_kernel<1><<<dim3(N1 / 128, TOKENS / 128), 256, 0, stream>>>(
      Xb, Bt1, D_DIM, gate, b1, bs1, Hm, nullptr, nullptr, nullptr);
  gemm_bt_kernel<2><<<dim3(D_DIM / 128, TOKENS / 128), 256, 0, stream>>>(
      Hm, Bt2, N1, gate, nullptr, nullptr, nullptr, b2, bs2, out);
}

// Round 2
// 278.635 us; speedup vs baseline: 1.5388x; 1.5388x over previous
//
#include <hip/hip_runtime.h>
#include <hip/hip_bf16.h>

// B=4, S=2048, D=1024, E=8, H=512, top-2 + shared expert
#define TOKENS 8192
#define D_DIM  1024
#define E_NUM  8
#define H_DIM  512
#define N1     4608            // E*H + H (Bt1 rows)
#define CAP    4096            // per-expert gathered-row capacity (~2048 expected, +52 sigma)
#define ETILES (CAP / 128)     // 32 tiles per expert segment
#define ROWS_CAP (E_NUM * CAP + TOKENS)  // 40960 gathered rows incl. shared segment

typedef __bf16 bf16_t;
typedef __bf16 bf16x8 __attribute__((ext_vector_type(8)));
typedef __bf16 bf16x4 __attribute__((ext_vector_type(4)));
typedef float  f32x4  __attribute__((ext_vector_type(4)));

__device__ __forceinline__ float gelu_exact(float v) {
  return 0.5f * v * (1.f + erff(v * 0.70710678118654752f));
}

// ---------------------------------------------------------------- routing
// one wave per token; fp64 accumulation so top-2 selection matches numpy ref.
__global__ __launch_bounds__(256) void routing_kernel(
    const float* __restrict__ x, const float* __restrict__ gW,
    const float* __restrict__ route_scale, float* __restrict__ gate) {
  int tok  = blockIdx.x * 4 + (threadIdx.x >> 6);
  int lane = threadIdx.x & 63;
  const float* xr = x + (size_t)tok * D_DIM;
  double p[E_NUM];
#pragma unroll
  for (int e = 0; e < E_NUM; ++e) p[e] = 0.0;
  for (int d = lane; d < D_DIM; d += 64) {
    double xv = (double)xr[d];
    const float* g = gW + (size_t)d * E_NUM;
#pragma unroll
    for (int e = 0; e < E_NUM; ++e) p[e] += xv * (double)g[e];
  }
#pragma unroll
  for (int off = 32; off > 0; off >>= 1) {
#pragma unroll
    for (int e = 0; e < E_NUM; ++e) p[e] += __shfl_xor(p[e], off, 64);
  }
  if (lane == 0) {
    double rs = (double)route_scale[0];
    double s[E_NUM];
#pragma unroll
    for (int e = 0; e < E_NUM; ++e) s[e] = rs / (1.0 + exp(-p[e]));
    int i1 = 0;
#pragma unroll
    for (int e = 1; e < E_NUM; ++e) if (s[e] > s[i1]) i1 = e;
    int i2 = (i1 == 0) ? 1 : 0;
#pragma unroll
    for (int e = 0; e < E_NUM; ++e) if (e != i1 && s[e] > s[i2]) i2 = e;
    double inv = 1.0 / (s[i1] + s[i2]);
    float o[E_NUM];
#pragma unroll
    for (int e = 0; e < E_NUM; ++e) o[e] = 0.f;
    o[i1] = (float)(s[i1] * inv);
    o[i2] = (float)(s[i2] * inv);
#pragma unroll
    for (int e = 0; e < E_NUM; ++e) gate[(size_t)tok * 8 + e] = o[e];
  }
}

// ---------------------------------------------------------------- cast x -> bf16
__global__ __launch_bounds__(256) void castx_kernel(
    const float* __restrict__ x, bf16_t* __restrict__ Xb, int n4) {
  int i = blockIdx.x * blockDim.x + threadIdx.x;
  for (; i < n4; i += gridDim.x * blockDim.x) {
    float4 v = ((const float4*)x)[i];
    bf16x4 o = { (bf16_t)v.x, (bf16_t)v.y, (bf16_t)v.z, (bf16_t)v.w };
    ((bf16x4*)Xb)[i] = o;
  }
}

// ------------------------------------------------- Bt1 (N1 x 1024): row n = e*512+h holds W1[e][:,h]; rows 4096+ = Ws1^T
__global__ __launch_bounds__(256) void repack1_kernel(
    const float* __restrict__ W1, const float* __restrict__ Ws1,
    bf16_t* __restrict__ Bt1) {
  __shared__ float tile[32][33];
  int k0 = blockIdx.x * 32, n0 = blockIdx.y * 32;
  int tx = threadIdx.x, ty = threadIdx.y;
#pragma unroll
  for (int i = 0; i < 4; ++i) {
    int kl = ty + i * 8;
    int n = n0 + tx, k = k0 + kl;
    float v;
    if (n0 < 4096) v = W1[(size_t)(n >> 9) * (D_DIM * H_DIM) + (size_t)k * H_DIM + (n & 511)];
    else           v = Ws1[(size_t)k * H_DIM + (n - 4096)];
    tile[kl][tx] = v;
  }
  __syncthreads();
#pragma unroll
  for (int i = 0; i < 4; ++i) {
    int nl = ty + i * 8;
    Bt1[(size_t)(n0 + nl) * D_DIM + k0 + tx] = (bf16_t)tile[tx][nl];
  }
}

// ------------------------------------------------- Bt2e[e][d][h]: per-expert W2[e]^T (e=8 -> Ws2^T), contiguous slices
__global__ __launch_bounds__(256) void repack2e_kernel(
    const float* __restrict__ W2, const float* __restrict__ Ws2,
    bf16_t* __restrict__ Bt2e) {
  __shared__ float tile[32][33];
  int d0 = blockIdx.x * 32, h0 = blockIdx.y * 32, e = blockIdx.z;
  int tx = threadIdx.x, ty = threadIdx.y;
#pragma unroll
  for (int i = 0; i < 4; ++i) {
    int hl = ty + i * 8;
    int h = h0 + hl, d = d0 + tx;
    float v = (e < E_NUM) ? W2[((size_t)e * H_DIM + h) * D_DIM + d]
                          : Ws2[(size_t)h * D_DIM + d];
    tile[hl][tx] = v;
  }
  __syncthreads();
#pragma unroll
  for (int i = 0; i < 4; ++i) {
    int dl = ty + i * 8;
    Bt2e[((size_t)e * D_DIM + (d0 + dl)) * H_DIM + h0 + tx] = (bf16_t)tile[tx][dl];
  }
}

// ---------------------------------------------------------------- deterministic list build
// block e<8: ordered compaction of tokens selecting expert e (ballot prefix, no atomics),
// padded to x128 with (tok=0, g=0). block 8: identity list for the shared expert.
__global__ __launch_bounds__(256) void listbuild_kernel(
    const float* __restrict__ gate, int* __restrict__ perm,
    float* __restrict__ grow, int* __restrict__ padcnt) {
  const int e = blockIdx.x;
  const int tid = threadIdx.x, lane = tid & 63, wid = tid >> 6;
  if (e == E_NUM) {
    for (int i = tid; i < TOKENS; i += 256) {
      perm[E_NUM * CAP + i] = i;
      grow[E_NUM * CAP + i] = 1.0f;
    }
    if (tid == 0) padcnt[E_NUM] = TOKENS;
    return;
  }
  __shared__ int wsum[4];
  const int base = e * CAP;
  int running = 0;
  for (int c = 0; c < TOKENS / 256; ++c) {
    int tok = c * 256 + tid;
    float gv = gate[(size_t)tok * 8 + e];
    bool f = gv > 0.f;
    unsigned long long m = __ballot(f);
    int lanepre = __popcll(m & ((1ull << lane) - 1ull));
    if (lane == 0) wsum[wid] = __popcll(m);
    __syncthreads();
    int wbase = 0;
#pragma unroll
    for (int w = 0; w < 4; ++w) if (w < wid) wbase += wsum[w];
    int tot = wsum[0] + wsum[1] + wsum[2] + wsum[3];
    if (f) {
      int p = base + running + wbase + lanepre;
      perm[p] = tok;
      grow[p] = gv;
    }
    running += tot;
    __syncthreads();
  }
  int pc = (running + 127) & ~127;
  for (int i = running + tid; i < pc; i += 256) { perm[base + i] = 0; grow[base + i] = 0.f; }
  if (tid == 0) padcnt[e] = pc;
}

// ---------------------------------------------------------------- m97-style GEMM core
// 128x128 tile, BK=32, 4 waves 2x2, 16x16x32 MFMA. ga*/gb* are per-lane global byte
// pointers for the two staged row-halves; advance 64 B per K-iter.
__device__ __forceinline__ void gemm_core(
    const char* ga0, const char* ga1, const char* gb0, const char* gb1,
    int kiters, bf16_t* sA, bf16_t* sB, int wave, int lane, int wr, int wc,
    f32x4 (&acc)[4][4]) {
  char* la0 = (char*)sA + wave * 1024;
  char* la1 = (char*)sA + 4096 + wave * 1024;
  char* lb0 = (char*)sB + wave * 1024;
  char* lb1 = (char*)sB + 4096 + wave * 1024;
  const int kb = (lane >> 4) * 16;
  const int ar = wr * 64 + (lane & 15);
  const int br = wc * 64 + (lane & 15);
  for (int kk = 0; kk < kiters; ++kk) {
    const size_t ko = (size_t)kk * 64;
    __builtin_amdgcn_global_load_lds(
        (const __attribute__((address_space(1))) void*)(ga0 + ko),
        (__attribute__((address_space(3))) void*)la0, 16, 0, 0);
    __builtin_amdgcn_global_load_lds(
        (const __attribute__((address_space(1))) void*)(ga1 + ko),
        (__attribute__((address_space(3))) void*)la1, 16, 0, 0);
    __builtin_amdgcn_global_load_lds(
        (const __attribute__((address_space(1))) void*)(gb0 + ko),
        (__attribute__((address_space(3))) void*)lb0, 16, 0, 0);
    __builtin_amdgcn_global_load_lds(
        (const __attribute__((address_space(1))) void*)(gb1 + ko),
        (__attribute__((address_space(3))) void*)lb1, 16, 0, 0);
    __syncthreads();
    bf16x8 af[4], bfv[4];
#pragma unroll
    for (int m = 0; m < 4; ++m)
      af[m] = *(const bf16x8*)((const char*)sA + (size_t)(ar + m * 16) * 64 + kb);
#pragma unroll
    for (int n = 0; n < 4; ++n)
      bfv[n] = *(const bf16x8*)((const char*)sB + (size_t)(br + n * 16) * 64 + kb);
#pragma unroll
    for (int m = 0; m < 4; ++m)
#pragma unroll
      for (int n = 0; n < 4; ++n)
        acc[m][n] = __builtin_amdgcn_mfma_f32_16x16x32_bf16(af[m], bfv[n], acc[m][n], 0, 0, 0);
    __syncthreads();
  }
}

// ---------------------------------------------------------------- GEMM1 sparse: H_s = gate * gelu(X[perm] @ W1[e]^T + b1)
__global__ __launch_bounds__(256) void gemm1e_kernel(
    const bf16_t* __restrict__ Xb, const bf16_t* __restrict__ Bt1,
    const int* __restrict__ perm, const float* __restrict__ grow,
    const int* __restrict__ padcnt,
    const float* __restrict__ b1, const float* __restrict__ bs1,
    bf16_t* __restrict__ Hs) {
  __shared__ bf16_t sA[128 * 32];
  __shared__ bf16_t sB[128 * 32];
  const int y = blockIdx.y;
  int e, lt;
  if (y < E_NUM * ETILES) { e = y >> 5; lt = y & 31; }
  else                    { e = E_NUM;  lt = y - E_NUM * ETILES; }
  if (lt * 128 >= padcnt[e]) return;   // whole block exits together
  const int rowbase = e * CAP + lt * 128;
  const int t = threadIdx.x, wave = t >> 6, lane = t & 63, wr = wave >> 1, wc = wave & 1;
  const int n0 = blockIdx.x * 128;     // N = 512
  const int r = t >> 2, cb = (t & 3) * 16;
  const int tok0 = perm[rowbase + r];
  const int tok1 = perm[rowbase + 64 + r];
  const char* ga0 = (const char*)Xb + (size_t)tok0 * 2048 + cb;
  const char* ga1 = (const char*)Xb + (size_t)tok1 * 2048 + cb;
  const bf16_t* W = Bt1 + (size_t)e * H_DIM * D_DIM;
  const char* gb0 = (const char*)W + (size_t)(n0 + r) * 2048 + cb;
  const char* gb1 = (const char*)W + (size_t)(n0 + 64 + r) * 2048 + cb;
  f32x4 acc[4][4];
#pragma unroll
  for (int i = 0; i < 4; ++i)
#pragma unroll
    for (int j = 0; j < 4; ++j) acc[i][j] = (f32x4){0.f, 0.f, 0.f, 0.f};
  gemm_core(ga0, ga1, gb0, gb1, D_DIM / 32, sA, sB, wave, lane, wr, wc, acc);

  const float* bias = (e < E_NUM) ? (b1 + e * H_DIM) : bs1;
#pragma unroll
  for (int m = 0; m < 4; ++m) {
    const int rloc = wr * 64 + m * 16 + (lane >> 4) * 4;
    float gr[4];
#pragma unroll
    for (int q = 0; q < 4; ++q) gr[q] = grow[rowbase + rloc + q];
#pragma unroll
    for (int n = 0; n < 4; ++n) {
      const int col = n0 + wc * 64 + n * 16 + (lane & 15);
      const float bv = bias[col];
#pragma unroll
      for (int q = 0; q < 4; ++q) {
        float v = gelu_exact(acc[m][n][q] + bv);
        Hs[(size_t)(rowbase + rloc + q) * H_DIM + col] = (bf16_t)(v * gr[q]);
      }
    }
  }
}

// ---------------------------------------------------------------- GEMM2: shared pass writes, expert pass atomic-adds
template <bool ATOMIC>
__global__ __launch_bounds__(256) void gemm2_kernel(
    const bf16_t* __restrict__ Hs, const bf16_t* __restrict__ Bt2e,
    const int* __restrict__ perm, const float* __restrict__ grow,
    const int* __restrict__ padcnt,
    const float* __restrict__ b2, const float* __restrict__ bs2,
    float* __restrict__ out) {
  __shared__ bf16_t sA[128 * 32];
  __shared__ bf16_t sB[128 * 32];
  const int y = blockIdx.y;
  int e, rowbase;
  if (ATOMIC) {
    e = y >> 5;
    const int lt = y & 31;
    if (lt * 128 >= padcnt[e]) return;
    rowbase = e * CAP + lt * 128;
  } else {
    e = E_NUM;
    rowbase = E_NUM * CAP + y * 128;
  }
  const int t = threadIdx.x, wave = t >> 6, lane = t & 63, wr = wave >> 1, wc = wave & 1;
  const int n0 = blockIdx.x * 128;     // N = 1024
  const int r = t >> 2, cb = (t & 3) * 16;
  const char* ga0 = (const char*)Hs + (size_t)(rowbase + r) * 1024 + cb;       // H stride 512 bf16
  const char* ga1 = (const char*)Hs + (size_t)(rowbase + 64 + r) * 1024 + cb;
  const bf16_t* W = Bt2e + (size_t)e * D_DIM * H_DIM;
  const char* gb0 = (const char*)W + (size_t)(n0 + r) * 1024 + cb;
  const char* gb1 = (const char*)W + (size_t)(n0 + 64 + r) * 1024 + cb;
  f32x4 acc[4][4];
#pragma unroll
  for (int i = 0; i < 4; ++i)
#pragma unroll
    for (int j = 0; j < 4; ++j) acc[i][j] = (f32x4){0.f, 0.f, 0.f, 0.f};
  gemm_core(ga0, ga1, gb0, gb1, H_DIM / 32, sA, sB, wave, lane, wr, wc, acc);

  if (ATOMIC) {
    const float* bb = b2 + (size_t)e * D_DIM;
#pragma unroll
    for (int m = 0; m < 4; ++m) {
      const int rloc = wr * 64 + m * 16 + (lane >> 4) * 4;
      int   tk[4];
      float gr[4];
#pragma unroll
      for (int q = 0; q < 4; ++q) {
        const int rr = rowbase + rloc + q;
        tk[q] = perm[rr];
        gr[q] = grow[rr];
      }
#pragma unroll
      for (int n = 0; n < 4; ++n) {
        const int col = n0 + wc * 64 + n * 16 + (lane & 15);
        const float bv = bb[col];
#pragma unroll
        for (int q = 0; q < 4; ++q)
          atomicAdd(out + (size_t)tk[q] * D_DIM + col, acc[m][n][q] + gr[q] * bv);
      }
    }
  } else {
#pragma unroll
    for (int m = 0; m < 4; ++m) {
      const int rloc = wr * 64 + m * 16 + (lane >> 4) * 4;
#pragma unroll
      for (int n = 0; n < 4; ++n) {
        const int col = n0 + wc * 64 + n * 16 + (lane & 15);
        const float bv = bs2[col];
#pragma unroll
        for (int q = 0; q < 4; ++q) {
          const int tok = rowbase - E_NUM * CAP + rloc + q;
          out[(size_t)tok * D_DIM + col] = acc[m][n][q] + bv;
        }
      }
    }
  }
}

// ---------------------------------------------------------------- launch
extern "C" void kernel_launch(void* const* d_in, const int* in_sizes, int n_in,
                              void* d_out, int out_size, void* d_ws, size_t ws_size,
                              hipStream_t stream) {
  (void)in_sizes; (void)n_in; (void)out_size; (void)ws_size;
  const float* x    = (const float*)d_in[0];
  const float* gW   = (const float*)d_in[1];
  const float* W1   = (const float*)d_in[2];
  const float* b1   = (const float*)d_in[3];
  const float* W2   = (const float*)d_in[4];
  const float* b2   = (const float*)d_in[5];
  const float* Ws1  = (const float*)d_in[6];
  const float* bs1  = (const float*)d_in[7];
  const float* Ws2  = (const float*)d_in[8];
  const float* bs2  = (const float*)d_in[9];
  const float* rsc  = (const float*)d_in[10];
  float* out = (float*)d_out;

  char* w = (char*)d_ws;
  float*  gate = (float*)w;  w += (size_t)TOKENS * 8 * 4;          // 256 KiB
  bf16_t* Xb   = (bf16_t*)w; w += (size_t)TOKENS * D_DIM * 2;      // 16.8 MB
  bf16_t* Bt1  = (bf16_t*)w; w += (size_t)N1 * D_DIM * 2;          // 9.4 MB
  bf16_t* Bt2e = (bf16_t*)w; w += (size_t)9 * D_DIM * H_DIM * 2;   // 9.4 MB
  bf16_t* Hs   = (bf16_t*)w; w += (size_t)ROWS_CAP * H_DIM * 2;    // 41.9 MB
  int*    perm = (int*)w;    w += (size_t)ROWS_CAP * 4;            // 160 KiB
  float*  grow = (float*)w;  w += (size_t)ROWS_CAP * 4;            // 160 KiB
  int*    padcnt = (int*)w;                                        // 36 B

  routing_kernel<<<TOKENS / 4, 256, 0, stream>>>(x, gW, rsc, gate);
  castx_kernel<<<2048, 256, 0, stream>>>(x, Xb, TOKENS * D_DIM / 4);
  repack1_kernel<<<dim3(D_DIM / 32, N1 / 32), dim3(32, 8), 0, stream>>>(W1, Ws1, Bt1);
  repack2e_kernel<<<dim3(D_DIM / 32, H_DIM / 32, 9), dim3(32, 8), 0, stream>>>(W2, Ws2, Bt2e);
  listbuild_kernel<<<E_NUM + 1, 256, 0, stream>>>(gate, perm, grow, padcnt);

  gemm1e_kernel<<<dim3(H_DIM / 128, E_NUM * ETILES + TOKENS / 128), 256, 0, stream>>>(
      Xb, Bt1, perm, grow, padcnt, b1, bs1, Hs);
  gemm2_kernel<false><<<dim3(D_DIM / 128, TOKENS / 128), 256, 0, stream>>>(
      Hs, Bt2e, perm, grow, padcnt, b2, bs2, out);
  gemm2_kernel<true><<<dim3(D_DIM / 128, E_NUM * ETILES), 256, 0, stream>>>(
      Hs, Bt2e, perm, grow, padcnt, b2, bs2, out);
}

// Round 3
// 232.086 us; speedup vs baseline: 1.8474x; 1.2006x over previous
//
#include <hip/hip_runtime.h>
#include <hip/hip_bf16.h>

// B=4, S=2048, D=1024, E=8, H=512, top-2 + shared expert
#define TOKENS 8192
#define D_DIM  1024
#define E_NUM  8
#define H_DIM  512
#define N1     4608            // E*H + H (Bt1 rows)
#define CAP    3072            // per-expert row capacity (~2048 expected, +26 sigma)
#define ETILES (CAP / 128)     // 24 tiles per expert segment
#define EXP_ROWS (E_NUM * CAP) // 24576 expert rows
#define SH_BASE  EXP_ROWS      // shared segment base in Hs row space
#define HS_ROWS (EXP_ROWS + TOKENS)  // 32768

typedef __bf16 bf16_t;
typedef __bf16 bf16x8 __attribute__((ext_vector_type(8)));
typedef __bf16 bf16x4 __attribute__((ext_vector_type(4)));
typedef float  f32x4  __attribute__((ext_vector_type(4)));

__device__ __forceinline__ float gelu_exact(float v) {
  return 0.5f * v * (1.f + erff(v * 0.70710678118654752f));
}

// ---------------------------------------------------------------- routing
__global__ __launch_bounds__(256) void routing_kernel(
    const float* __restrict__ x, const float* __restrict__ gW,
    const float* __restrict__ route_scale, float* __restrict__ gate) {
  int tok  = blockIdx.x * 4 + (threadIdx.x >> 6);
  int lane = threadIdx.x & 63;
  const float* xr = x + (size_t)tok * D_DIM;
  double p[E_NUM];
#pragma unroll
  for (int e = 0; e < E_NUM; ++e) p[e] = 0.0;
  for (int d = lane; d < D_DIM; d += 64) {
    double xv = (double)xr[d];
    const float* g = gW + (size_t)d * E_NUM;
#pragma unroll
    for (int e = 0; e < E_NUM; ++e) p[e] += xv * (double)g[e];
  }
#pragma unroll
  for (int off = 32; off > 0; off >>= 1) {
#pragma unroll
    for (int e = 0; e < E_NUM; ++e) p[e] += __shfl_xor(p[e], off, 64);
  }
  if (lane == 0) {
    double rs = (double)route_scale[0];
    double s[E_NUM];
#pragma unroll
    for (int e = 0; e < E_NUM; ++e) s[e] = rs / (1.0 + exp(-p[e]));
    int i1 = 0;
#pragma unroll
    for (int e = 1; e < E_NUM; ++e) if (s[e] > s[i1]) i1 = e;
    int i2 = (i1 == 0) ? 1 : 0;
#pragma unroll
    for (int e = 0; e < E_NUM; ++e) if (e != i1 && s[e] > s[i2]) i2 = e;
    double inv = 1.0 / (s[i1] + s[i2]);
    float o[E_NUM];
#pragma unroll
    for (int e = 0; e < E_NUM; ++e) o[e] = 0.f;
    o[i1] = (float)(s[i1] * inv);
    o[i2] = (float)(s[i2] * inv);
#pragma unroll
    for (int e = 0; e < E_NUM; ++e) gate[(size_t)tok * 8 + e] = o[e];
  }
}

// ---------------------------------------------------------------- cast x -> bf16
__global__ __launch_bounds__(256) void castx_kernel(
    const float* __restrict__ x, bf16_t* __restrict__ Xb, int n4) {
  int i = blockIdx.x * blockDim.x + threadIdx.x;
  for (; i < n4; i += gridDim.x * blockDim.x) {
    float4 v = ((const float4*)x)[i];
    bf16x4 o = { (bf16_t)v.x, (bf16_t)v.y, (bf16_t)v.z, (bf16_t)v.w };
    ((bf16x4*)Xb)[i] = o;
  }
}

// ------------------------------------------------- Bt1 (N1 x 1024): row n=e*512+h holds W1[e][:,h]; rows 4096+ = Ws1^T
__global__ __launch_bounds__(256) void repack1_kernel(
    const float* __restrict__ W1, const float* __restrict__ Ws1,
    bf16_t* __restrict__ Bt1) {
  __shared__ float tile[32][33];
  int k0 = blockIdx.x * 32, n0 = blockIdx.y * 32;
  int tx = threadIdx.x, ty = threadIdx.y;
#pragma unroll
  for (int i = 0; i < 4; ++i) {
    int kl = ty + i * 8;
    int n = n0 + tx, k = k0 + kl;
    float v;
    if (n0 < 4096) v = W1[(size_t)(n >> 9) * (D_DIM * H_DIM) + (size_t)k * H_DIM + (n & 511)];
    else           v = Ws1[(size_t)k * H_DIM + (n - 4096)];
    tile[kl][tx] = v;
  }
  __syncthreads();
#pragma unroll
  for (int i = 0; i < 4; ++i) {
    int nl = ty + i * 8;
    Bt1[(size_t)(n0 + nl) * D_DIM + k0 + tx] = (bf16_t)tile[tx][nl];
  }
}

// ------------------------------------------------- Bt2e[e][d][h]: per-expert W2[e]^T (e=8 -> Ws2^T)
__global__ __launch_bounds__(256) void repack2e_kernel(
    const float* __restrict__ W2, const float* __restrict__ Ws2,
    bf16_t* __restrict__ Bt2e) {
  __shared__ float tile[32][33];
  int d0 = blockIdx.x * 32, h0 = blockIdx.y * 32, e = blockIdx.z;
  int tx = threadIdx.x, ty = threadIdx.y;
#pragma unroll
  for (int i = 0; i < 4; ++i) {
    int hl = ty + i * 8;
    int h = h0 + hl, d = d0 + tx;
    float v = (e < E_NUM) ? W2[((size_t)e * H_DIM + h) * D_DIM + d]
                          : Ws2[(size_t)h * D_DIM + d];
    tile[hl][tx] = v;
  }
  __syncthreads();
#pragma unroll
  for (int i = 0; i < 4; ++i) {
    int dl = ty + i * 8;
    Bt2e[((size_t)e * D_DIM + (d0 + dl)) * H_DIM + h0 + tx] = (bf16_t)tile[tx][dl];
  }
}

// ---------------------------------------------------------------- list build (deterministic, no atomics)
// block e<8: ordered compaction of tokens with gate[tok][e]>0, padded to x128.
// Also records tok2row[tok][slot] (slot = # lower-indexed selected experts, 0 or 1).
__global__ __launch_bounds__(256) void listbuild_kernel(
    const float* __restrict__ gate, int* __restrict__ perm,
    float* __restrict__ grow, int* __restrict__ tok2row,
    int* __restrict__ padcnt) {
  const int e = blockIdx.x;
  const int tid = threadIdx.x, lane = tid & 63, wid = tid >> 6;
  __shared__ int wsum[4];
  const int base = e * CAP;
  int running = 0;
  for (int c = 0; c < TOKENS / 256; ++c) {
    int tok = c * 256 + tid;
    float gv = gate[(size_t)tok * 8 + e];
    bool f = gv > 0.f;
    unsigned long long m = __ballot(f);
    int lanepre = __popcll(m & ((1ull << lane) - 1ull));
    if (lane == 0) wsum[wid] = __popcll(m);
    __syncthreads();
    int wbase = 0;
#pragma unroll
    for (int w = 0; w < 4; ++w) if (w < wid) wbase += wsum[w];
    int tot = wsum[0] + wsum[1] + wsum[2] + wsum[3];
    if (f) {
      int idx = running + wbase + lanepre;
      if (idx < CAP) {
        perm[base + idx] = tok;
        grow[base + idx] = gv;
        int slot = 0;
#pragma unroll
        for (int e2 = 0; e2 < E_NUM; ++e2)
          if (e2 < e && gate[(size_t)tok * 8 + e2] > 0.f) ++slot;
        tok2row[tok * 2 + (slot & 1)] = base + idx;
      }
    }
    running += tot;
    __syncthreads();
  }
  if (running > CAP) running = CAP;
  int pc = (running + 127) & ~127;
  for (int i = running + tid; i < pc; i += 256) { perm[base + i] = 0; grow[base + i] = 0.f; }
  if (tid == 0) padcnt[e] = pc;
}

// ---------------------------------------------------------------- 2-phase double-buffered GEMM core
// 128x128 tile, BK=32, 4 waves 2x2, 16x16x32 MFMA. Counted vmcnt (never 0 mid-loop):
// next tile's 4 global_load_lds fly while current tile computes.
__device__ __forceinline__ void gemm_core(
    const char* ga0, const char* ga1, const char* gb0, const char* gb1,
    int kiters, bf16_t* sA, bf16_t* sB, int wave, int lane, int wr, int wc,
    f32x4 (&acc)[4][4]) {
  const int kb = (lane >> 4) * 16;
  const int ar = wr * 64 + (lane & 15);
  const int br = wc * 64 + (lane & 15);
  auto stage = [&](int buf, int kk) {
    const size_t ko = (size_t)kk * 64;
    char* la = (char*)sA + buf * 8192 + wave * 1024;
    char* lb = (char*)sB + buf * 8192 + wave * 1024;
    __builtin_amdgcn_global_load_lds(
        (const __attribute__((address_space(1))) void*)(ga0 + ko),
        (__attribute__((address_space(3))) void*)la, 16, 0, 0);
    __builtin_amdgcn_global_load_lds(
        (const __attribute__((address_space(1))) void*)(ga1 + ko),
        (__attribute__((address_space(3))) void*)(la + 4096), 16, 0, 0);
    __builtin_amdgcn_global_load_lds(
        (const __attribute__((address_space(1))) void*)(gb0 + ko),
        (__attribute__((address_space(3))) void*)lb, 16, 0, 0);
    __builtin_amdgcn_global_load_lds(
        (const __attribute__((address_space(1))) void*)(gb1 + ko),
        (__attribute__((address_space(3))) void*)(lb + 4096), 16, 0, 0);
  };
  stage(0, 0);
  for (int kk = 0; kk < kiters; ++kk) {
    const int cur = kk & 1;
    if (kk + 1 < kiters) {
      stage(cur ^ 1, kk + 1);
      asm volatile("s_waitcnt vmcnt(4)" ::: "memory");  // current tile's loads done
    } else {
      asm volatile("s_waitcnt vmcnt(0)" ::: "memory");
    }
    __builtin_amdgcn_s_barrier();
    asm volatile("" ::: "memory");   // keep ds_reads below the barrier
    const char* bA = (const char*)sA + cur * 8192;
    const char* bB = (const char*)sB + cur * 8192;
    bf16x8 af[4], bfv[4];
#pragma unroll
    for (int m = 0; m < 4; ++m)
      af[m] = *(const bf16x8*)(bA + (size_t)(ar + m * 16) * 64 + kb);
#pragma unroll
    for (int n = 0; n < 4; ++n)
      bfv[n] = *(const bf16x8*)(bB + (size_t)(br + n * 16) * 64 + kb);
#pragma unroll
    for (int m = 0; m < 4; ++m)
#pragma unroll
      for (int n = 0; n < 4; ++n)
        acc[m][n] = __builtin_amdgcn_mfma_f32_16x16x32_bf16(af[m], bfv[n], acc[m][n], 0, 0, 0);
    asm volatile("" ::: "memory");   // keep next stage below this barrier
    __builtin_amdgcn_s_barrier();
  }
}

// ---------------------------------------------------------------- GEMM1: Hs = gate * gelu(X[perm] @ W1[e]^T + b1)
__global__ __launch_bounds__(256) void gemm1e_kernel(
    const bf16_t* __restrict__ Xb, const bf16_t* __restrict__ Bt1,
    const int* __restrict__ perm, const float* __restrict__ grow,
    const int* __restrict__ padcnt,
    const float* __restrict__ b1, const float* __restrict__ bs1,
    bf16_t* __restrict__ Hs) {
  __shared__ bf16_t sA[2 * 128 * 32];
  __shared__ bf16_t sB[2 * 128 * 32];
  const int y = blockIdx.y;
  const int t = threadIdx.x, wave = t >> 6, lane = t & 63, wr = wave >> 1, wc = wave & 1;
  const int n0 = blockIdx.x * 128;   // N = 512
  const int r = t >> 2, cb = (t & 3) * 16;
  int e, rowbase, tok0, tok1;
  if (y < E_NUM * ETILES) {
    e = y / ETILES;
    const int lt = y - e * ETILES;
    if (lt * 128 >= padcnt[e]) return;
    rowbase = e * CAP + lt * 128;
    tok0 = perm[rowbase + r];
    tok1 = perm[rowbase + 64 + r];
  } else {
    e = E_NUM;
    const int st = y - E_NUM * ETILES;
    rowbase = SH_BASE + st * 128;
    tok0 = st * 128 + r;
    tok1 = st * 128 + 64 + r;
  }
  const char* ga0 = (const char*)Xb + (size_t)tok0 * 2048 + cb;
  const char* ga1 = (const char*)Xb + (size_t)tok1 * 2048 + cb;
  const bf16_t* W = Bt1 + (size_t)e * H_DIM * D_DIM;
  const char* gb0 = (const char*)W + (size_t)(n0 + r) * 2048 + cb;
  const char* gb1 = (const char*)W + (size_t)(n0 + 64 + r) * 2048 + cb;
  f32x4 acc[4][4];
#pragma unroll
  for (int i = 0; i < 4; ++i)
#pragma unroll
    for (int j = 0; j < 4; ++j) acc[i][j] = (f32x4){0.f, 0.f, 0.f, 0.f};
  gemm_core(ga0, ga1, gb0, gb1, D_DIM / 32, sA, sB, wave, lane, wr, wc, acc);

  const float* bias = (e < E_NUM) ? (b1 + e * H_DIM) : bs1;
#pragma unroll
  for (int m = 0; m < 4; ++m) {
    const int rloc = wr * 64 + m * 16 + (lane >> 4) * 4;
    float gr[4];
#pragma unroll
    for (int q = 0; q < 4; ++q)
      gr[q] = (e < E_NUM) ? grow[rowbase + rloc + q] : 1.0f;
#pragma unroll
    for (int n = 0; n < 4; ++n) {
      const int col = n0 + wc * 64 + n * 16 + (lane & 15);
      const float bv = bias[col];
#pragma unroll
      for (int q = 0; q < 4; ++q) {
        float v = gelu_exact(acc[m][n][q] + bv);
        Hs[(size_t)(rowbase + rloc + q) * H_DIM + col] = (bf16_t)(v * gr[q]);
      }
    }
  }
}

// ---------------------------------------------------------------- GEMM2 unified (plain stores only):
// expert tiles: Ys[row] = acc + grow*b2[e];  shared tiles: out[tok] = acc + bs2
__global__ __launch_bounds__(256) void gemm2_kernel(
    const bf16_t* __restrict__ Hs, const bf16_t* __restrict__ Bt2e,
    const float* __restrict__ grow, const int* __restrict__ padcnt,
    const float* __restrict__ b2, const float* __restrict__ bs2,
    float* __restrict__ Ys, float* __restrict__ out) {
  __shared__ bf16_t sA[2 * 128 * 32];
  __shared__ bf16_t sB[2 * 128 * 32];
  const int y = blockIdx.y;
  const int t = threadIdx.x, wave = t >> 6, lane = t & 63, wr = wave >> 1, wc = wave & 1;
  const int n0 = blockIdx.x * 128;   // N = 1024
  const int r = t >> 2, cb = (t & 3) * 16;
  int e, rowbase;
  if (y < E_NUM * ETILES) {
    e = y / ETILES;
    const int lt = y - e * ETILES;
    if (lt * 128 >= padcnt[e]) return;
    rowbase = e * CAP + lt * 128;
  } else {
    e = E_NUM;
    rowbase = SH_BASE + (y - E_NUM * ETILES) * 128;
  }
  const char* ga0 = (const char*)Hs + (size_t)(rowbase + r) * 1024 + cb;
  const char* ga1 = (const char*)Hs + (size_t)(rowbase + 64 + r) * 1024 + cb;
  const bf16_t* W = Bt2e + (size_t)e * D_DIM * H_DIM;
  const char* gb0 = (const char*)W + (size_t)(n0 + r) * 1024 + cb;
  const char* gb1 = (const char*)W + (size_t)(n0 + 64 + r) * 1024 + cb;
  f32x4 acc[4][4];
#pragma unroll
  for (int i = 0; i < 4; ++i)
#pragma unroll
    for (int j = 0; j < 4; ++j) acc[i][j] = (f32x4){0.f, 0.f, 0.f, 0.f};
  gemm_core(ga0, ga1, gb0, gb1, H_DIM / 32, sA, sB, wave, lane, wr, wc, acc);

  if (e < E_NUM) {
    const float* bb = b2 + (size_t)e * D_DIM;
#pragma unroll
    for (int m = 0; m < 4; ++m) {
      const int rloc = wr * 64 + m * 16 + (lane >> 4) * 4;
      float gr[4];
#pragma unroll
      for (int q = 0; q < 4; ++q) gr[q] = grow[rowbase + rloc + q];
#pragma unroll
      for (int n = 0; n < 4; ++n) {
        const int col = n0 + wc * 64 + n * 16 + (lane & 15);
        const float bv = bb[col];
#pragma unroll
        for (int q = 0; q < 4; ++q)
          Ys[(size_t)(rowbase + rloc + q) * D_DIM + col] = acc[m][n][q] + gr[q] * bv;
      }
    }
  } else {
    const int tokbase = rowbase - SH_BASE;
#pragma unroll
    for (int m = 0; m < 4; ++m) {
      const int rloc = wr * 64 + m * 16 + (lane >> 4) * 4;
#pragma unroll
      for (int n = 0; n < 4; ++n) {
        const int col = n0 + wc * 64 + n * 16 + (lane & 15);
        const float bv = bs2[col];
#pragma unroll
        for (int q = 0; q < 4; ++q)
          out[(size_t)(tokbase + rloc + q) * D_DIM + col] = acc[m][n][q] + bv;
      }
    }
  }
}

// ---------------------------------------------------------------- combine: out[tok] += Ys[r0] + Ys[r1]
__global__ __launch_bounds__(256) void combine_kernel(
    const float* __restrict__ Ys, const int* __restrict__ tok2row,
    float* __restrict__ out) {
  const int total = TOKENS * (D_DIM / 4);
  for (int i = blockIdx.x * 256 + threadIdx.x; i < total; i += gridDim.x * 256) {
    const int tok = i >> 8, q = i & 255;
    int r0 = tok2row[tok * 2], r1 = tok2row[tok * 2 + 1];
    r0 = (r0 < 0) ? 0 : (r0 >= EXP_ROWS ? EXP_ROWS - 1 : r0);
    r1 = (r1 < 0) ? 0 : (r1 >= EXP_ROWS ? EXP_ROWS - 1 : r1);
    const float4 a = ((const float4*)Ys)[(size_t)r0 * 256 + q];
    const float4 b = ((const float4*)Ys)[(size_t)r1 * 256 + q];
    float4 o = ((float4*)out)[(size_t)tok * 256 + q];
    o.x += a.x + b.x; o.y += a.y + b.y; o.z += a.z + b.z; o.w += a.w + b.w;
    ((float4*)out)[(size_t)tok * 256 + q] = o;
  }
}

// ---------------------------------------------------------------- launch
extern "C" void kernel_launch(void* const* d_in, const int* in_sizes, int n_in,
                              void* d_out, int out_size, void* d_ws, size_t ws_size,
                              hipStream_t stream) {
  (void)in_sizes; (void)n_in; (void)out_size; (void)ws_size;
  const float* x    = (const float*)d_in[0];
  const float* gW   = (const float*)d_in[1];
  const float* W1   = (const float*)d_in[2];
  const float* b1   = (const float*)d_in[3];
  const float* W2   = (const float*)d_in[4];
  const float* b2   = (const float*)d_in[5];
  const float* Ws1  = (const float*)d_in[6];
  const float* bs1  = (const float*)d_in[7];
  const float* Ws2  = (const float*)d_in[8];
  const float* bs2  = (const float*)d_in[9];
  const float* rsc  = (const float*)d_in[10];
  float* out = (float*)d_out;

  char* w = (char*)d_ws;
  float*  gate = (float*)w;  w += (size_t)TOKENS * 8 * 4;            // 0.25 MB
  bf16_t* Xb   = (bf16_t*)w; w += (size_t)TOKENS * D_DIM * 2;        // 16.8 MB
  bf16_t* Bt1  = (bf16_t*)w; w += (size_t)N1 * D_DIM * 2;            // 9.4 MB
  bf16_t* Bt2e = (bf16_t*)w; w += (size_t)9 * D_DIM * H_DIM * 2;     // 9.4 MB
  bf16_t* Hs   = (bf16_t*)w; w += (size_t)HS_ROWS * H_DIM * 2;       // 33.6 MB
  float*  Ys   = (float*)w;  w += (size_t)EXP_ROWS * D_DIM * 4;      // 100.7 MB
  int*    perm = (int*)w;    w += (size_t)EXP_ROWS * 4;              // 98 KB
  float*  grow = (float*)w;  w += (size_t)EXP_ROWS * 4;              // 98 KB
  int*    tok2row = (int*)w; w += (size_t)TOKENS * 2 * 4;            // 64 KB
  int*    padcnt  = (int*)w;                                         // 32 B

  routing_kernel<<<TOKENS / 4, 256, 0, stream>>>(x, gW, rsc, gate);
  castx_kernel<<<2048, 256, 0, stream>>>(x, Xb, TOKENS * D_DIM / 4);
  repack1_kernel<<<dim3(D_DIM / 32, N1 / 32), dim3(32, 8), 0, stream>>>(W1, Ws1, Bt1);
  repack2e_kernel<<<dim3(D_DIM / 32, H_DIM / 32, 9), dim3(32, 8), 0, stream>>>(W2, Ws2, Bt2e);
  listbuild_kernel<<<E_NUM, 256, 0, stream>>>(gate, perm, grow, tok2row, padcnt);

  gemm1e_kernel<<<dim3(H_DIM / 128, E_NUM * ETILES + TOKENS / 128), 256, 0, stream>>>(
      Xb, Bt1, perm, grow, padcnt, b1, bs1, Hs);
  gemm2_kernel<<<dim3(D_DIM / 128, E_NUM * ETILES + TOKENS / 128), 256, 0, stream>>>(
      Hs, Bt2e, grow, padcnt, b2, bs2, Ys, out);
  combine_kernel<<<2048, 256, 0, stream>>>(Ys, tok2row, out);
}